// Round 8
// baseline (588.118 us; speedup 1.0000x reference)
//
#include <hip/hip_runtime.h>

#define N_NODES 100000
#define N_PAIRS 50000
#define N_EDGES 1600000
#define D 32
#define ED 8
#define NEG_SLOPE 0.01f
#define NBLK 98                       // scan blocks over N at 1024/blk
#define XB_N 131072                   // xb rows incl. sentinel space
#define SENT_MASK 0x1FFFF             // pad src (0xFFFFFFFF) -> node 131071
#define SLOT_CAP (N_EDGES + 15 * N_NODES + 16)  // Σ16·ceil(deg/16)+16 ≤ E+15N+16 (deterministic)

typedef unsigned int uint;
typedef unsigned short ushort;
typedef __attribute__((ext_vector_type(8))) short short8;
typedef __attribute__((ext_vector_type(16))) float f32x16;

__device__ __forceinline__ uint bf16_rne(float f) {
    uint u = __float_as_uint(f);
    return (u + 0x7fffu + ((u >> 16) & 1u)) >> 16;
}
__device__ __forceinline__ uint pack2(float lo, float hi) {
    return bf16_rne(lo) | (bf16_rne(hi) << 16);
}
__device__ __forceinline__ float bf_lo(uint u) { return __uint_as_float(u << 16); }
__device__ __forceinline__ float bf_hi(uint u) { return __uint_as_float(u & 0xffff0000u); }
__device__ __forceinline__ float bf_us(ushort u) { return __uint_as_float(((uint)u) << 16); }

// ---- pack x -> bf16 into xbA; fill sentinel/pad region of BOTH buffers ----
__global__ __launch_bounds__(256) void pack_fill_kernel(
    const float* __restrict__ x, ushort* __restrict__ xbA, ushort* __restrict__ xbB)
{
    int i = blockIdx.x * 256 + threadIdx.x;          // over XB_N*D/4 uint2
    if (i >= XB_N * D / 4) return;
    if (i < N_NODES * D / 4) {
        float4 f = ((const float4*)x)[i];
        ((uint2*)xbA)[i] = make_uint2(pack2(f.x, f.y), pack2(f.z, f.w));
    } else {
        uint2 pad = make_uint2(0xCE6ECE6Eu, 0xCE6ECE6Eu);  // bf16 -9.99e8
        ((uint2*)xbA)[i] = pad;
        ((uint2*)xbB)[i] = pad;
    }
}

// ---- degree histogram ----
__global__ __launch_bounds__(256) void hist_kernel(
    const int* __restrict__ dst, int* __restrict__ deg)
{
    int i = blockIdx.x * 256 + threadIdx.x;          // over E/4
    if (i >= N_EDGES / 4) return;
    int4 dd = ((const int4*)dst)[i];
    atomicAdd(&deg[dd.x], 1);
    atomicAdd(&deg[dd.y], 1);
    atomicAdd(&deg[dd.z], 1);
    atomicAdd(&deg[dd.w], 1);
}

// ---- 3-phase scan over transformed degrees ----
template<int SHIFT>
__global__ __launch_bounds__(1024) void scan_phase1(
    const int* __restrict__ deg, int* __restrict__ bsums)
{
    __shared__ int s[1024];
    int t = threadIdx.x;
    int i = blockIdx.x * 1024 + t;
    int v = (i < N_NODES) ? ((deg[i] + ((1 << SHIFT) - 1)) >> SHIFT) : 0;
    s[t] = v;
    __syncthreads();
    for (int off = 512; off > 0; off >>= 1) {
        if (t < off) s[t] += s[t + off];
        __syncthreads();
    }
    if (t == 0) bsums[blockIdx.x] = s[0];
}

__global__ __launch_bounds__(128) void scan_phase2(int* __restrict__ bsums)
{
    __shared__ int s[128];
    int t = threadIdx.x;
    int v = (t < NBLK) ? bsums[t] : 0;
    s[t] = v;
    __syncthreads();
    for (int off = 1; off < 128; off <<= 1) {
        int u = (t >= off) ? s[t - off] : 0;
        __syncthreads();
        s[t] += u;
        __syncthreads();
    }
    if (t < NBLK) bsums[t] = s[t] - v;  // exclusive
}

template<int SHIFT, int BIAS>
__global__ __launch_bounds__(1024) void scan_phase3(
    const int* __restrict__ deg, const int* __restrict__ bsums,
    int* __restrict__ base, int* __restrict__ cur)
{
    __shared__ int s[1024];
    int t = threadIdx.x;
    int i = blockIdx.x * 1024 + t;
    int v = (i < N_NODES) ? ((deg[i] + ((1 << SHIFT) - 1)) >> SHIFT) : 0;
    s[t] = v;
    __syncthreads();
    for (int off = 1; off < 1024; off <<= 1) {
        int u = (t >= off) ? s[t - off] : 0;
        __syncthreads();
        s[t] += u;
        __syncthreads();
    }
    int excl = bsums[blockIdx.x] + s[t] - v;
    int val = BIAS + (excl << SHIFT);
    if (i < N_NODES) { base[i] = val; cur[i] = val; }
    else if (i == N_NODES) base[i] = val;
}

// ---- MFMA-tier scatter: 32B record {ea bf16x8, src, pad12}, 2 edges/thread ----
__global__ __launch_bounds__(256) void scatter32_kernel(
    const int*   __restrict__ src,
    const int*   __restrict__ dst,
    const float* __restrict__ edge_attr,
    int*         __restrict__ cur,
    uint*        __restrict__ rec)
{
    int tid = blockIdx.x * 256 + threadIdx.x;
    if (tid >= N_EDGES / 2) return;
    const float4* ea4 = (const float4*)edge_attr;
#pragma unroll
    for (int u = 0; u < 2; ++u) {
        int e = tid + u * (N_EDGES / 2);
        int pos = atomicAdd(&cur[dst[e]], 1);
        float4 a = ea4[(long)e * 2];
        float4 c = ea4[(long)e * 2 + 1];
        uint* r = rec + (size_t)pos * 8;
        *(uint4*)r = make_uint4(pack2(a.x, a.y), pack2(a.z, a.w),
                                pack2(c.x, c.y), pack2(c.z, c.w));
        r[4] = (uint)src[e];
    }
}

// ---- MFMA GINE layer: wave = node pair, 32-edge batches through the matrix pipe
__global__ __launch_bounds__(256) void gine_mfma_kernel(
    const ushort* __restrict__ xb_in,
    ushort*       __restrict__ xb_out,
    float*        __restrict__ f32_out,
    const int*    __restrict__ nbase,
    const uint*   __restrict__ rec,
    const float*  __restrict__ W,    // [32][32] fp32
    const float*  __restrict__ b,    // [32]
    const float*  __restrict__ We,   // [8][32]
    const float*  __restrict__ be)   // [32]
{
    __shared__ float W_s[D * D];
    const int t = threadIdx.x;
    for (int i = t; i < D * D; i += 256) W_s[i] = W[i];

    const int l    = t & 63;
    const int half = l >> 5;
    const int d    = l & 31;        // col for C / row m for A-load

    // B fragment: We_pad[16][32] bf16; rows 0-7 = We, row 8 = be, rest 0.
    short8 bfrag;
#pragma unroll
    for (int j = 0; j < 8; ++j) {
        int k = half * 8 + j;
        float v = (k < ED) ? We[k * D + d] : (k == ED ? be[d] : 0.0f);
        bfrag[j] = (short)bf16_rne(v);
    }
    const float bd = b[d];
    __syncthreads();

    const int p = blockIdx.x * 4 + (t >> 6);   // pair id
    if (p >= N_PAIRS) return;
    const int nA = 2 * p, nB = 2 * p + 1;
    const int bA = nbase[nA], bB = nbase[nB], bE = nbase[nB + 1];
    const int nbA = (bB - bA) >> 4;
    const int nbB = (bE - bB) >> 4;
    const int tmax = max(nbA, nbB);

    const int m      = d;                                     // A-row this lane stages
    const int mybase = (m < 16) ? bA + m : bB + (m & 15);
    const int mynb   = (m < 16) ? nbA : nbB;

    const short8 bias = {(short)0x3F80, 0, 0, 0, 0, 0, 0, 0}; // 1.0 at k=8
    float accA = 0.0f, accB = 0.0f;

    for (int tt = 0; tt < tmax; ++tt) {
        int slot = (tt < mynb) ? mybase + (tt << 4) : (m & 15);  // sentinel slots 0-15
        const uint* rp = rec + (size_t)slot * 8;
        uint4 eau = *(const uint4*)rp;
        uint srcv = rp[4];

        short8 afrag = half ? bias : __builtin_bit_cast(short8, eau);
        f32x16 zacc = 0.0f;
        f32x16 e16 = __builtin_amdgcn_mfma_f32_32x32x16_bf16(afrag, bfrag, zacc, 0, 0, 0);

        float xv[16];
#pragma unroll
        for (int reg = 0; reg < 16; ++reg) {
            int row = (reg & 3) + 8 * (reg >> 2) + 4 * half;   // C-layout row
            int sr = __shfl((int)srcv, row, 32) & SENT_MASK;
            xv[reg] = bf_us(xb_in[(uint)sr * D + d]);
        }
#pragma unroll
        for (int reg = 0; reg < 16; ++reg) {
            float msg = fmaxf(xv[reg] + e16[reg], 0.0f);       // NaN ea / -1e9 pad -> 0
            if (reg < 8) accA += msg; else accB += msg;
        }
    }
    accA += __shfl_xor(accA, 32);   // combine lane-halves (width 64)
    accB += __shfl_xor(accB, 32);

    const int  myn   = half ? nB : nA;
    const float accm = half ? accB : accA;
    float h = bf_us(xb_in[(uint)myn * D + d]) + accm;

    float o = bd;
#pragma unroll
    for (int k = 0; k < D; ++k)
        o += __shfl(h, k, 32) * W_s[k * D + d];
    o = o > 0.0f ? o : NEG_SLOPE * o;
    xb_out[(uint)myn * D + d] = (ushort)bf16_rne(o);
    if (f32_out) f32_out[(uint)myn * D + d] = o;
}

// =================== round-5 middle tier ===================
__global__ __launch_bounds__(256) void scatter_rec_kernel(
    const int* __restrict__ src, const int* __restrict__ dst,
    const float* __restrict__ edge_attr, int* __restrict__ offs,
    uint* __restrict__ rec)
{
    int e = blockIdx.x * 256 + threadIdx.x;
    if (e >= N_EDGES) return;
    int pos = atomicAdd(&offs[dst[e]], 1);
    const float4* ea4 = (const float4*)edge_attr;
    float4 a = ea4[(long)e * 2];
    float4 c = ea4[(long)e * 2 + 1];
    uint* r = rec + (long)pos * 8;
    uint4 w0 = make_uint4((uint)src[e], pack2(a.x, a.y), pack2(a.z, a.w), pack2(c.x, c.y));
    *(uint4*)r = w0;
    r[4] = pack2(c.z, c.w);
}

__global__ __launch_bounds__(256) void gine_fused2_kernel(
    const ushort* __restrict__ xb_in, ushort* __restrict__ xb_out,
    float* __restrict__ f32_out, const int* __restrict__ row_ptr,
    const uint* __restrict__ rec,
    const float* __restrict__ W, const float* __restrict__ b,
    const float* __restrict__ We, const float* __restrict__ be)
{
    __shared__ float W_s[D * D];
    __shared__ float We_s[ED * D];
    __shared__ float b_s[D];
    __shared__ float be_s[D];
    const int t = threadIdx.x;
    for (int i = t; i < D * D; i += 256) W_s[i] = W[i];
    if (t < ED * D) We_s[t] = We[t];
    if (t < D) { b_s[t] = b[t]; be_s[t] = be[t]; }
    __syncthreads();
    const int n = blockIdx.x * 8 + (t >> 5);
    const int d = t & 31;
    if (n >= N_NODES) return;
    float wer[ED];
#pragma unroll
    for (int k = 0; k < ED; ++k) wer[k] = We_s[k * D + d];
    const float bed = be_s[d];
    const int row = row_ptr[n], rend = row_ptr[n + 1];
    float selfx = bf_us(xb_in[n * D + d]);
    float acc = 0.0f;
    for (int pos = row; pos < rend; pos += 8) {
        const int rem = rend - pos;
        const uint2* rp = (const uint2*)(rec + (long)pos * 8);
        uint2 v = rp[d];
        int srcs[8];
#pragma unroll
        for (int j = 0; j < 8; ++j) srcs[j] = __shfl((int)v.x, 4 * j, 32);
        const int s0 = srcs[0];
        float xv[8];
#pragma unroll
        for (int j = 0; j < 8; ++j) {
            int sj = (j < rem) ? srcs[j] : s0;
            xv[j] = bf_us(xb_in[sj * D + d]);
        }
#pragma unroll
        for (int j = 0; j < 8; ++j) {
            uint u01 = (uint)__shfl((int)v.y, 4 * j, 32);
            uint u23 = (uint)__shfl((int)v.x, 4 * j + 1, 32);
            uint u45 = (uint)__shfl((int)v.y, 4 * j + 1, 32);
            uint u67 = (uint)__shfl((int)v.x, 4 * j + 2, 32);
            float e = bed;
            e += bf_lo(u01) * wer[0]; e += bf_hi(u01) * wer[1];
            e += bf_lo(u23) * wer[2]; e += bf_hi(u23) * wer[3];
            e += bf_lo(u45) * wer[4]; e += bf_hi(u45) * wer[5];
            e += bf_lo(u67) * wer[6]; e += bf_hi(u67) * wer[7];
            float msg = fmaxf(xv[j] + e, 0.0f);
            acc += (j < rem) ? msg : 0.0f;
        }
    }
    float h = selfx + acc;
    float o = b_s[d];
#pragma unroll
    for (int k = 0; k < D; ++k)
        o += __shfl(h, k, 32) * W_s[k * D + d];
    o = o > 0.0f ? o : NEG_SLOPE * o;
    xb_out[n * D + d] = (ushort)bf16_rne(o);
    if (f32_out) f32_out[n * D + d] = o;
}

// =================== round-1 fallback ===================
__global__ __launch_bounds__(256) void gine_edge_kernel(
    const float* __restrict__ x, const float* __restrict__ edge_attr,
    const float* __restrict__ We, const float* __restrict__ be,
    const int* __restrict__ src, const int* __restrict__ dst,
    float* __restrict__ agg)
{
    __shared__ float We_s[ED * D];
    __shared__ float be_s[D];
    int t = threadIdx.x;
    if (t < ED * D) We_s[t] = We[t];
    if (t < D) be_s[t] = be[t];
    __syncthreads();
    long gtid = (long)blockIdx.x * blockDim.x + t;
    int e = (int)(gtid >> 5), d = (int)(gtid & 31);
    if (e >= N_EDGES) return;
    int s = src[e], dn = dst[e];
    float acc = be_s[d];
#pragma unroll
    for (int k = 0; k < ED; ++k)
        acc += edge_attr[(long)e * ED + k] * We_s[k * D + d];
    float m = fmaxf(x[(long)s * D + d] + acc, 0.0f);
    atomicAdd(&agg[(long)dn * D + d], m);
}

__global__ __launch_bounds__(256) void gine_node_kernel(
    float* __restrict__ x, const float* __restrict__ agg,
    const float* __restrict__ W, const float* __restrict__ b)
{
    __shared__ float W_s[D * D];
    __shared__ float b_s[D];
    int t = threadIdx.x;
    for (int i = t; i < D * D; i += 256) W_s[i] = W[i];
    if (t < D) b_s[t] = b[t];
    __syncthreads();
    long gtid = (long)blockIdx.x * blockDim.x + t;
    int n = (int)(gtid >> 5), d = (int)(gtid & 31);
    if (n >= N_NODES) return;
    float h = x[(long)n * D + d] + agg[(long)n * D + d];
    float acc = b_s[d];
#pragma unroll
    for (int k = 0; k < D; ++k)
        acc += __shfl(h, k, D) * W_s[k * D + d];
    x[(long)n * D + d] = acc > 0.0f ? acc : NEG_SLOPE * acc;
}

// =================== launch ===================
extern "C" void kernel_launch(void* const* d_in, const int* in_sizes, int n_in,
                              void* d_out, int out_size, void* d_ws, size_t ws_size,
                              hipStream_t stream) {
    const float* x_in      = (const float*)d_in[0];
    const float* edge_attr = (const float*)d_in[1];
    const float* W         = (const float*)d_in[2];
    const float* b         = (const float*)d_in[3];
    const float* We        = (const float*)d_in[4];
    const float* be        = (const float*)d_in[5];
    const int*   ei        = (const int*)d_in[6];
    const int* src = ei;
    const int* dst = ei + N_EDGES;

    const size_t xbytes  = (size_t)N_NODES * D * sizeof(float);
    const size_t xbbytes = (size_t)XB_N * D * sizeof(ushort);   // 8.39 MB

    auto align = [](size_t v) { return (v + 255) & ~(size_t)255; };
    size_t off_xba  = 0;
    size_t off_xbb  = align(off_xba + xbbytes);
    size_t off_deg  = align(off_xbb + xbbytes);                   // N ints
    size_t off_nb   = align(off_deg + N_NODES * sizeof(int));     // base (N+1)
    size_t off_cur  = align(off_nb + (N_NODES + 1) * sizeof(int));// cursors (N)
    size_t off_bs   = align(off_cur + N_NODES * sizeof(int));     // bsums 128
    size_t off_rec  = align(off_bs + 128 * sizeof(int));
    size_t need_big = off_rec + (size_t)SLOT_CAP * 32 + 256;
    size_t need_mid = off_rec + (size_t)N_EDGES * 32 + 256;

    char* ws = (char*)d_ws;
    ushort* xbA   = (ushort*)(ws + off_xba);
    ushort* xbB   = (ushort*)(ws + off_xbb);
    int*   deg    = (int*)   (ws + off_deg);
    int*   nbase  = (int*)   (ws + off_nb);
    int*   cur    = (int*)   (ws + off_cur);
    int*   bsums  = (int*)   (ws + off_bs);
    uint*  rec    = (uint*)  (ws + off_rec);
    float* xout   = (float*)d_out;

    if (ws_size >= need_big) {
        pack_fill_kernel<<<(XB_N * D / 4 + 255) / 256, 256, 0, stream>>>(x_in, xbA, xbB);
        hipMemsetAsync(deg, 0, N_NODES * sizeof(int), stream);
        hipMemsetAsync(rec, 0xFF, (size_t)SLOT_CAP * 32, stream);  // pad slots -> NaN/sentinel
        hist_kernel<<<(N_EDGES / 4 + 255) / 256, 256, 0, stream>>>(dst, deg);
        scan_phase1<4><<<NBLK, 1024, 0, stream>>>(deg, bsums);
        scan_phase2<<<1, 128, 0, stream>>>(bsums);
        scan_phase3<4, 16><<<NBLK, 1024, 0, stream>>>(deg, bsums, nbase, cur);
        scatter32_kernel<<<(N_EDGES / 2 + 255) / 256, 256, 0, stream>>>(
            src, dst, edge_attr, cur, rec);

        dim3 blk(256), grid((N_PAIRS + 3) / 4);
        gine_mfma_kernel<<<grid, blk, 0, stream>>>(xbA, xbB, nullptr, nbase, rec,
            W, b, We, be);
        gine_mfma_kernel<<<grid, blk, 0, stream>>>(xbB, xbA, nullptr, nbase, rec,
            W + D * D, b + D, We + ED * D, be + D);
        gine_mfma_kernel<<<grid, blk, 0, stream>>>(xbA, xbB, xout, nbase, rec,
            W + 2 * D * D, b + 2 * D, We + 2 * ED * D, be + 2 * D);
    } else if (ws_size >= need_mid) {
        pack_fill_kernel<<<(XB_N * D / 4 + 255) / 256, 256, 0, stream>>>(x_in, xbA, xbB);
        hipMemsetAsync(deg, 0, N_NODES * sizeof(int), stream);
        hist_kernel<<<(N_EDGES / 4 + 255) / 256, 256, 0, stream>>>(dst, deg);
        scan_phase1<0><<<NBLK, 1024, 0, stream>>>(deg, bsums);
        scan_phase2<<<1, 128, 0, stream>>>(bsums);
        scan_phase3<0, 0><<<NBLK, 1024, 0, stream>>>(deg, bsums, nbase, cur);
        scatter_rec_kernel<<<(N_EDGES + 255) / 256, 256, 0, stream>>>(
            src, dst, edge_attr, cur, rec);
        dim3 blk(256), grid((N_NODES + 7) / 8);
        gine_fused2_kernel<<<grid, blk, 0, stream>>>(xbA, xbB, nullptr, nbase, rec,
            W, b, We, be);
        gine_fused2_kernel<<<grid, blk, 0, stream>>>(xbB, xbA, nullptr, nbase, rec,
            W + D * D, b + D, We + ED * D, be + D);
        gine_fused2_kernel<<<grid, blk, 0, stream>>>(xbA, xbB, xout, nbase, rec,
            W + 2 * D * D, b + 2 * D, We + 2 * ED * D, be + 2 * D);
    } else {
        float* x = (float*)d_out;
        float* agg = (float*)d_ws;
        hipMemcpyAsync(x, x_in, xbytes, hipMemcpyDeviceToDevice, stream);
        dim3 eblk(256), egrid(((long)N_EDGES * D + 255) / 256);
        dim3 nblk(256), ngrid(((long)N_NODES * D + 255) / 256);
        for (int l = 0; l < 3; ++l) {
            hipMemsetAsync(agg, 0, xbytes, stream);
            gine_edge_kernel<<<egrid, eblk, 0, stream>>>(
                x, edge_attr, We + (size_t)l * ED * D, be + (size_t)l * D, src, dst, agg);
            gine_node_kernel<<<ngrid, nblk, 0, stream>>>(
                x, agg, W + (size_t)l * D * D, b + (size_t)l * D);
        }
    }
}

// Round 9
// 496.150 us; speedup vs baseline: 1.1854x; 1.1854x over previous
//
#include <hip/hip_runtime.h>

#define N_NODES 100000
#define N_EDGES 1600000
#define D 32
#define ED 8
#define NEG_SLOPE 0.01f
#define CB 782                                   // coarse buckets = dst>>7
#define BKN 128                                  // nodes per bucket
#define A_EPB 8192                               // edges per A-block
#define A_NB ((N_EDGES + A_EPB - 1) / A_EPB)     // 196
#define NBLK 98                                  // mid-tier scan blocks

typedef unsigned int uint;
typedef unsigned short ushort;

__device__ __forceinline__ uint bf16_rne(float f) {
    uint u = __float_as_uint(f);
    return (u + 0x7fffu + ((u >> 16) & 1u)) >> 16;
}
__device__ __forceinline__ uint pack2(float lo, float hi) {
    return bf16_rne(lo) | (bf16_rne(hi) << 16);
}
__device__ __forceinline__ float bf_lo(uint u) { return __uint_as_float(u << 16); }
__device__ __forceinline__ float bf_hi(uint u) { return __uint_as_float(u & 0xffff0000u); }
__device__ __forceinline__ float bf_us(ushort u) { return __uint_as_float(((uint)u) << 16); }

// ---------------- x -> bf16 pack ----------------
__global__ __launch_bounds__(256) void pack_x_kernel(
    const float* __restrict__ x, ushort* __restrict__ xb)
{
    int i = blockIdx.x * 256 + threadIdx.x;     // over N*D/4
    if (i >= N_NODES * D / 4) return;
    float4 f = ((const float4*)x)[i];
    ((uint2*)xb)[i] = make_uint2(pack2(f.x, f.y), pack2(f.z, f.w));
}

// ---- A1: per-block coarse histogram (LDS), write count matrix ----
__global__ __launch_bounds__(256) void countA_kernel(
    const int* __restrict__ dst, int* __restrict__ cntM)
{
    __shared__ int h[CB];
    const int t = threadIdx.x;
    for (int i = t; i < CB; i += 256) h[i] = 0;
    __syncthreads();
    const int e0 = blockIdx.x * A_EPB;
    for (int j = 0; j < A_EPB; j += 256) {
        int e = e0 + j + t;
        if (e < N_EDGES) atomicAdd(&h[dst[e] >> 7], 1);
    }
    __syncthreads();
    for (int i = t; i < CB; i += 256) cntM[blockIdx.x * CB + i] = h[i];
}

// ---- S1: per-bucket exclusive scan over blocks; emit totals ----
__global__ __launch_bounds__(256) void scanS1_kernel(
    const int* __restrict__ cntM, int* __restrict__ exclM, int* __restrict__ btot)
{
    __shared__ int s[256];
    const int t = threadIdx.x;
    const int b = blockIdx.x;
    int v = (t < A_NB) ? cntM[t * CB + b] : 0;
    s[t] = v;
    __syncthreads();
    for (int off = 1; off < 256; off <<= 1) {
        int u = (t >= off) ? s[t - off] : 0;
        __syncthreads();
        s[t] += u;
        __syncthreads();
    }
    if (t < A_NB) exclM[t * CB + b] = s[t] - v;
    if (t == 255) btot[b] = s[255];
}

// ---- S2: exclusive scan of bucket totals -> bucket bases ----
__global__ __launch_bounds__(1024) void scanS2_kernel(
    const int* __restrict__ btot, int* __restrict__ bbase, int* __restrict__ row_ptr)
{
    __shared__ int s[1024];
    const int t = threadIdx.x;
    int v = (t < CB) ? btot[t] : 0;
    s[t] = v;
    __syncthreads();
    for (int off = 1; off < 1024; off <<= 1) {
        int u = (t >= off) ? s[t - off] : 0;
        __syncthreads();
        s[t] += u;
        __syncthreads();
    }
    if (t < CB) bbase[t] = s[t] - v;
    if (t == 0) row_ptr[N_NODES] = N_EDGES;
}

// ---- A3: coarse scatter into reserved dense ranges (zero global atomics) ----
// rec_tmp record (32B): w0=src, w1..4=ea bf16x8, w5=dst
__global__ __launch_bounds__(256) void scatterA_kernel(
    const int*   __restrict__ src,
    const int*   __restrict__ dst,
    const float* __restrict__ edge_attr,
    const int*   __restrict__ exclM,
    const int*   __restrict__ bbase,
    uint*        __restrict__ rec_tmp)
{
    __shared__ int cur[CB];
    const int t = threadIdx.x;
    for (int i = t; i < CB; i += 256)
        cur[i] = bbase[i] + exclM[blockIdx.x * CB + i];
    __syncthreads();
    const int e0 = blockIdx.x * A_EPB;
    const float4* ea4 = (const float4*)edge_attr;
    for (int j = 0; j < A_EPB; j += 256) {
        int e = e0 + j + t;
        if (e >= N_EDGES) continue;
        int dn = dst[e];
        int pos = atomicAdd(&cur[dn >> 7], 1);
        float4 a = ea4[(long)e * 2];
        float4 c = ea4[(long)e * 2 + 1];
        uint* r = rec_tmp + (size_t)pos * 8;
        *(uint4*)r = make_uint4((uint)src[e], pack2(a.x, a.y),
                                pack2(a.z, a.w), pack2(c.x, c.y));
        *(uint2*)(r + 4) = make_uint2(pack2(c.z, c.w), (uint)dn);
    }
}

// ---- B: per-bucket fine scatter + exact row_ptr; writes confined to 65KB ----
__global__ __launch_bounds__(256) void fineB_kernel(
    const uint* __restrict__ rec_tmp,
    const int*  __restrict__ bbase,
    int*        __restrict__ row_ptr,
    uint*       __restrict__ rec)
{
    __shared__ int h[BKN];
    __shared__ int ex[BKN];
    const int t = threadIdx.x;
    const int b = blockIdx.x;
    const int e0 = bbase[b];
    const int e1 = (b == CB - 1) ? N_EDGES : bbase[b + 1];

    if (t < BKN) h[t] = 0;
    __syncthreads();
    for (int r = e0 + t; r < e1; r += 256)
        atomicAdd(&h[rec_tmp[(size_t)r * 8 + 5] & (BKN - 1)], 1);
    __syncthreads();
    if (t < BKN) ex[t] = h[t];
    __syncthreads();
    for (int off = 1; off < BKN; off <<= 1) {
        int u = (t < BKN && t >= off) ? ex[t - off] : 0;
        __syncthreads();
        if (t < BKN) ex[t] += u;
        __syncthreads();
    }
    if (t < BKN) {
        int excl = ex[t] - h[t];           // exclusive prefix
        int n = b * BKN + t;
        if (n < N_NODES) row_ptr[n] = e0 + excl;
        h[t] = e0 + excl;                  // global cursor
    }
    __syncthreads();
    for (int r = e0 + t; r < e1; r += 256) {
        const uint* rt = rec_tmp + (size_t)r * 8;
        uint4 w0 = *(const uint4*)rt;
        uint2 w1 = *(const uint2*)(rt + 4);
        int pos = atomicAdd(&h[w1.y & (BKN - 1)], 1);
        uint* ro = rec + (size_t)pos * 8;
        *(uint4*)ro = w0;                  // src, ea01, ea23, ea45
        ro[4] = w1.x;                      // ea67
    }
}

// ---------------- fused GINE layer (r5-proven) ----------------
__global__ __launch_bounds__(256) void gine_fused2_kernel(
    const ushort* __restrict__ xb_in, ushort* __restrict__ xb_out,
    float* __restrict__ f32_out, const int* __restrict__ row_ptr,
    const uint* __restrict__ rec,
    const float* __restrict__ W, const float* __restrict__ b,
    const float* __restrict__ We, const float* __restrict__ be)
{
    __shared__ float W_s[D * D];
    __shared__ float We_s[ED * D];
    __shared__ float b_s[D];
    __shared__ float be_s[D];
    const int t = threadIdx.x;
    for (int i = t; i < D * D; i += 256) W_s[i] = W[i];
    if (t < ED * D) We_s[t] = We[t];
    if (t < D) { b_s[t] = b[t]; be_s[t] = be[t]; }
    __syncthreads();
    const int n = blockIdx.x * 8 + (t >> 5);
    const int d = t & 31;
    if (n >= N_NODES) return;
    float wer[ED];
#pragma unroll
    for (int k = 0; k < ED; ++k) wer[k] = We_s[k * D + d];
    const float bed = be_s[d];
    const int row = row_ptr[n], rend = row_ptr[n + 1];
    float selfx = bf_us(xb_in[n * D + d]);
    float acc = 0.0f;
    for (int pos = row; pos < rend; pos += 8) {
        const int rem = rend - pos;
        const uint2* rp = (const uint2*)(rec + (long)pos * 8);
        uint2 v = rp[d];
        int srcs[8];
#pragma unroll
        for (int j = 0; j < 8; ++j) srcs[j] = __shfl((int)v.x, 4 * j, 32);
        const int s0 = srcs[0];
        float xv[8];
#pragma unroll
        for (int j = 0; j < 8; ++j) {
            int sj = (j < rem) ? srcs[j] : s0;
            xv[j] = bf_us(xb_in[sj * D + d]);
        }
#pragma unroll
        for (int j = 0; j < 8; ++j) {
            uint u01 = (uint)__shfl((int)v.y, 4 * j, 32);
            uint u23 = (uint)__shfl((int)v.x, 4 * j + 1, 32);
            uint u45 = (uint)__shfl((int)v.y, 4 * j + 1, 32);
            uint u67 = (uint)__shfl((int)v.x, 4 * j + 2, 32);
            float e = bed;
            e += bf_lo(u01) * wer[0]; e += bf_hi(u01) * wer[1];
            e += bf_lo(u23) * wer[2]; e += bf_hi(u23) * wer[3];
            e += bf_lo(u45) * wer[4]; e += bf_hi(u45) * wer[5];
            e += bf_lo(u67) * wer[6]; e += bf_hi(u67) * wer[7];
            float msg = fmaxf(xv[j] + e, 0.0f);
            acc += (j < rem) ? msg : 0.0f;
        }
    }
    float h = selfx + acc;
    float o = b_s[d];
#pragma unroll
    for (int k = 0; k < D; ++k)
        o += __shfl(h, k, 32) * W_s[k * D + d];
    o = o > 0.0f ? o : NEG_SLOPE * o;
    xb_out[n * D + d] = (ushort)bf16_rne(o);
    if (f32_out) f32_out[n * D + d] = o;
}

// =================== mid-tier (r5 CSR build) ===================
__global__ __launch_bounds__(256) void hist_kernel(
    const int* __restrict__ dst, int* __restrict__ deg)
{
    int i = blockIdx.x * 256 + threadIdx.x;
    if (i >= N_EDGES / 4) return;
    int4 dd = ((const int4*)dst)[i];
    atomicAdd(&deg[dd.x], 1);
    atomicAdd(&deg[dd.y], 1);
    atomicAdd(&deg[dd.z], 1);
    atomicAdd(&deg[dd.w], 1);
}

__global__ __launch_bounds__(1024) void scan_phase1(
    const int* __restrict__ deg, int* __restrict__ bsums)
{
    __shared__ int s[1024];
    int t = threadIdx.x;
    int i = blockIdx.x * 1024 + t;
    s[t] = (i < N_NODES) ? deg[i] : 0;
    __syncthreads();
    for (int off = 512; off > 0; off >>= 1) {
        if (t < off) s[t] += s[t + off];
        __syncthreads();
    }
    if (t == 0) bsums[blockIdx.x] = s[0];
}

__global__ __launch_bounds__(128) void scan_phase2(int* __restrict__ bsums)
{
    __shared__ int s[128];
    int t = threadIdx.x;
    int v = (t < NBLK) ? bsums[t] : 0;
    s[t] = v;
    __syncthreads();
    for (int off = 1; off < 128; off <<= 1) {
        int u = (t >= off) ? s[t - off] : 0;
        __syncthreads();
        s[t] += u;
        __syncthreads();
    }
    if (t < NBLK) bsums[t] = s[t] - v;
}

__global__ __launch_bounds__(1024) void scan_phase3(
    const int* __restrict__ deg, const int* __restrict__ bsums,
    int* __restrict__ row_ptr, int* __restrict__ offs)
{
    __shared__ int s[1024];
    int t = threadIdx.x;
    int i = blockIdx.x * 1024 + t;
    int v = (i < N_NODES) ? deg[i] : 0;
    s[t] = v;
    __syncthreads();
    for (int off = 1; off < 1024; off <<= 1) {
        int u = (t >= off) ? s[t - off] : 0;
        __syncthreads();
        s[t] += u;
        __syncthreads();
    }
    int excl = bsums[blockIdx.x] + s[t] - v;
    if (i < N_NODES) { row_ptr[i] = excl; offs[i] = excl; }
    else if (i == N_NODES) row_ptr[i] = excl;
}

__global__ __launch_bounds__(256) void scatter_rec_kernel(
    const int* __restrict__ src, const int* __restrict__ dst,
    const float* __restrict__ edge_attr, int* __restrict__ offs,
    uint* __restrict__ rec)
{
    int e = blockIdx.x * 256 + threadIdx.x;
    if (e >= N_EDGES) return;
    int pos = atomicAdd(&offs[dst[e]], 1);
    const float4* ea4 = (const float4*)edge_attr;
    float4 a = ea4[(long)e * 2];
    float4 c = ea4[(long)e * 2 + 1];
    uint* r = rec + (long)pos * 8;
    *(uint4*)r = make_uint4((uint)src[e], pack2(a.x, a.y), pack2(a.z, a.w), pack2(c.x, c.y));
    r[4] = pack2(c.z, c.w);
}

// =================== round-1 fallback ===================
__global__ __launch_bounds__(256) void gine_edge_kernel(
    const float* __restrict__ x, const float* __restrict__ edge_attr,
    const float* __restrict__ We, const float* __restrict__ be,
    const int* __restrict__ src, const int* __restrict__ dst,
    float* __restrict__ agg)
{
    __shared__ float We_s[ED * D];
    __shared__ float be_s[D];
    int t = threadIdx.x;
    if (t < ED * D) We_s[t] = We[t];
    if (t < D) be_s[t] = be[t];
    __syncthreads();
    long gtid = (long)blockIdx.x * blockDim.x + t;
    int e = (int)(gtid >> 5), d = (int)(gtid & 31);
    if (e >= N_EDGES) return;
    int s = src[e], dn = dst[e];
    float acc = be_s[d];
#pragma unroll
    for (int k = 0; k < ED; ++k)
        acc += edge_attr[(long)e * ED + k] * We_s[k * D + d];
    float m = fmaxf(x[(long)s * D + d] + acc, 0.0f);
    atomicAdd(&agg[(long)dn * D + d], m);
}

__global__ __launch_bounds__(256) void gine_node_kernel(
    float* __restrict__ x, const float* __restrict__ agg,
    const float* __restrict__ W, const float* __restrict__ b)
{
    __shared__ float W_s[D * D];
    __shared__ float b_s[D];
    int t = threadIdx.x;
    for (int i = t; i < D * D; i += 256) W_s[i] = W[i];
    if (t < D) b_s[t] = b[t];
    __syncthreads();
    long gtid = (long)blockIdx.x * blockDim.x + t;
    int n = (int)(gtid >> 5), d = (int)(gtid & 31);
    if (n >= N_NODES) return;
    float h = x[(long)n * D + d] + agg[(long)n * D + d];
    float acc = b_s[d];
#pragma unroll
    for (int k = 0; k < D; ++k)
        acc += __shfl(h, k, D) * W_s[k * D + d];
    x[(long)n * D + d] = acc > 0.0f ? acc : NEG_SLOPE * acc;
}

// =================== launch ===================
extern "C" void kernel_launch(void* const* d_in, const int* in_sizes, int n_in,
                              void* d_out, int out_size, void* d_ws, size_t ws_size,
                              hipStream_t stream) {
    const float* x_in      = (const float*)d_in[0];
    const float* edge_attr = (const float*)d_in[1];
    const float* W         = (const float*)d_in[2];
    const float* b         = (const float*)d_in[3];
    const float* We        = (const float*)d_in[4];
    const float* be        = (const float*)d_in[5];
    const int*   ei        = (const int*)d_in[6];
    const int* src = ei;
    const int* dst = ei + N_EDGES;

    const size_t xbytes  = (size_t)N_NODES * D * sizeof(float);
    const size_t xbbytes = (size_t)N_NODES * D * sizeof(ushort);  // 6.4 MB

    auto align = [](size_t v) { return (v + 255) & ~(size_t)255; };
    size_t off_xba  = 0;
    size_t off_rp   = align(off_xba + xbbytes);                    // row_ptr N+1
    size_t off_cnt  = align(off_rp + (N_NODES + 1) * sizeof(int)); // cntM / deg
    size_t off_excl = align(off_cnt + (size_t)A_NB * CB * sizeof(int));  // exclM / offs
    size_t off_bt   = align(off_excl + (size_t)A_NB * CB * sizeof(int)); // btot / bsums
    size_t off_bb   = align(off_bt + CB * sizeof(int));            // bbase
    size_t off_rec  = align(off_bb + CB * sizeof(int));            // rec (E+8 recs)
    size_t off_rtmp = align(off_rec + ((size_t)N_EDGES + 8) * 32); // rec_tmp / xbB
    size_t need_big = off_rtmp + (size_t)N_EDGES * 32 + 256;
    size_t need_mid = off_rtmp + xbbytes + 256;

    char* ws = (char*)d_ws;
    ushort* xbA    = (ushort*)(ws + off_xba);
    int*   row_ptr = (int*)   (ws + off_rp);
    int*   cntM    = (int*)   (ws + off_cnt);
    int*   exclM   = (int*)   (ws + off_excl);
    int*   btot    = (int*)   (ws + off_bt);
    int*   bbase   = (int*)   (ws + off_bb);
    uint*  rec     = (uint*)  (ws + off_rec);
    uint*  rec_tmp = (uint*)  (ws + off_rtmp);
    ushort* xbB    = (ushort*)(ws + off_rtmp);   // aliases rec_tmp (dead after fineB)
    float* xout    = (float*)d_out;

    if (ws_size >= need_big) {
        pack_x_kernel<<<(N_NODES * D / 4 + 255) / 256, 256, 0, stream>>>(x_in, xbA);
        countA_kernel<<<A_NB, 256, 0, stream>>>(dst, cntM);
        scanS1_kernel<<<CB, 256, 0, stream>>>(cntM, exclM, btot);
        scanS2_kernel<<<1, 1024, 0, stream>>>(btot, bbase, row_ptr);
        scatterA_kernel<<<A_NB, 256, 0, stream>>>(src, dst, edge_attr, exclM, bbase, rec_tmp);
        fineB_kernel<<<CB, 256, 0, stream>>>(rec_tmp, bbase, row_ptr, rec);

        dim3 blk(256), grid((N_NODES + 7) / 8);
        gine_fused2_kernel<<<grid, blk, 0, stream>>>(xbA, xbB, nullptr, row_ptr, rec,
            W, b, We, be);
        gine_fused2_kernel<<<grid, blk, 0, stream>>>(xbB, xbA, nullptr, row_ptr, rec,
            W + D * D, b + D, We + ED * D, be + D);
        gine_fused2_kernel<<<grid, blk, 0, stream>>>(xbA, xbB, xout, row_ptr, rec,
            W + 2 * D * D, b + 2 * D, We + 2 * ED * D, be + 2 * D);
    } else if (ws_size >= need_mid) {
        int* deg  = cntM;
        int* offs = exclM;
        int* bsums = btot;
        pack_x_kernel<<<(N_NODES * D / 4 + 255) / 256, 256, 0, stream>>>(x_in, xbA);
        hipMemsetAsync(deg, 0, N_NODES * sizeof(int), stream);
        hist_kernel<<<(N_EDGES / 4 + 255) / 256, 256, 0, stream>>>(dst, deg);
        scan_phase1<<<NBLK, 1024, 0, stream>>>(deg, bsums);
        scan_phase2<<<1, 128, 0, stream>>>(bsums);
        scan_phase3<<<NBLK, 1024, 0, stream>>>(deg, bsums, row_ptr, offs);
        scatter_rec_kernel<<<(N_EDGES + 255) / 256, 256, 0, stream>>>(
            src, dst, edge_attr, offs, rec);
        dim3 blk(256), grid((N_NODES + 7) / 8);
        gine_fused2_kernel<<<grid, blk, 0, stream>>>(xbA, xbB, nullptr, row_ptr, rec,
            W, b, We, be);
        gine_fused2_kernel<<<grid, blk, 0, stream>>>(xbB, xbA, nullptr, row_ptr, rec,
            W + D * D, b + D, We + ED * D, be + D);
        gine_fused2_kernel<<<grid, blk, 0, stream>>>(xbA, xbB, xout, row_ptr, rec,
            W + 2 * D * D, b + 2 * D, We + 2 * ED * D, be + 2 * D);
    } else {
        float* x = (float*)d_out;
        float* agg = (float*)d_ws;
        hipMemcpyAsync(x, x_in, xbytes, hipMemcpyDeviceToDevice, stream);
        dim3 eblk(256), egrid(((long)N_EDGES * D + 255) / 256);
        dim3 nblk(256), ngrid(((long)N_NODES * D + 255) / 256);
        for (int l = 0; l < 3; ++l) {
            hipMemsetAsync(agg, 0, xbytes, stream);
            gine_edge_kernel<<<egrid, eblk, 0, stream>>>(
                x, edge_attr, We + (size_t)l * ED * D, be + (size_t)l * D, src, dst, agg);
            gine_node_kernel<<<ngrid, nblk, 0, stream>>>(
                x, agg, W + (size_t)l * D * D, b + (size_t)l * D);
        }
    }
}

// Round 10
// 480.657 us; speedup vs baseline: 1.2236x; 1.0322x over previous
//
#include <hip/hip_runtime.h>

#define N_NODES 100000
#define N_EDGES 1600000
#define D 32
#define ED 8
#define NEG_SLOPE 0.01f
#define CB 782                                   // coarse buckets = dst>>7
#define BKN 128                                  // nodes per bucket
#define A_EPB 8192                               // edges per A-block
#define A_NB ((N_EDGES + A_EPB - 1) / A_EPB)     // 196
#define NBLK 98                                  // mid-tier scan blocks

typedef unsigned int uint;
typedef unsigned short ushort;
typedef __fp16 half2v __attribute__((ext_vector_type(2)));

__device__ __forceinline__ uint bf16_rne(float f) {
    uint u = __float_as_uint(f);
    return (u + 0x7fffu + ((u >> 16) & 1u)) >> 16;
}
__device__ __forceinline__ uint pack2(float lo, float hi) {
    return bf16_rne(lo) | (bf16_rne(hi) << 16);
}
__device__ __forceinline__ float bf_lo(uint u) { return __uint_as_float(u << 16); }
__device__ __forceinline__ float bf_hi(uint u) { return __uint_as_float(u & 0xffff0000u); }
__device__ __forceinline__ float bf_us(ushort u) { return __uint_as_float(((uint)u) << 16); }

// pack two floats -> f16x2 (RNE)
__device__ __forceinline__ uint ph2(float lo, float hi) {
    __fp16 l = (__fp16)lo, h = (__fp16)hi;
    return (uint)__builtin_bit_cast(ushort, l) | ((uint)__builtin_bit_cast(ushort, h) << 16);
}

#if defined(__has_builtin) && __has_builtin(__builtin_amdgcn_fdot2)
__device__ __forceinline__ float fdot2f(uint u, half2v w, float c) {
    return __builtin_amdgcn_fdot2(__builtin_bit_cast(half2v, u), w, c, false);
}
#else
__device__ __forceinline__ float fdot2f(uint u, half2v w, float c) {
    half2v a = __builtin_bit_cast(half2v, u);
    return c + (float)a.x * (float)w.x + (float)a.y * (float)w.y;
}
#endif

// ---------------- x -> bf16 pack ----------------
__global__ __launch_bounds__(256) void pack_x_kernel(
    const float* __restrict__ x, ushort* __restrict__ xb)
{
    int i = blockIdx.x * 256 + threadIdx.x;     // over N*D/4
    if (i >= N_NODES * D / 4) return;
    float4 f = ((const float4*)x)[i];
    ((uint2*)xb)[i] = make_uint2(pack2(f.x, f.y), pack2(f.z, f.w));
}

// ---- A1: per-block coarse histogram (LDS), write count matrix ----
__global__ __launch_bounds__(256) void countA_kernel(
    const int* __restrict__ dst, int* __restrict__ cntM)
{
    __shared__ int h[CB];
    const int t = threadIdx.x;
    for (int i = t; i < CB; i += 256) h[i] = 0;
    __syncthreads();
    const int e0 = blockIdx.x * A_EPB;
    for (int j = 0; j < A_EPB; j += 256) {
        int e = e0 + j + t;
        if (e < N_EDGES) atomicAdd(&h[dst[e] >> 7], 1);
    }
    __syncthreads();
    for (int i = t; i < CB; i += 256) cntM[blockIdx.x * CB + i] = h[i];
}

// ---- S1: per-bucket exclusive scan over blocks; emit totals ----
__global__ __launch_bounds__(256) void scanS1_kernel(
    const int* __restrict__ cntM, int* __restrict__ exclM, int* __restrict__ btot)
{
    __shared__ int s[256];
    const int t = threadIdx.x;
    const int b = blockIdx.x;
    int v = (t < A_NB) ? cntM[t * CB + b] : 0;
    s[t] = v;
    __syncthreads();
    for (int off = 1; off < 256; off <<= 1) {
        int u = (t >= off) ? s[t - off] : 0;
        __syncthreads();
        s[t] += u;
        __syncthreads();
    }
    if (t < A_NB) exclM[t * CB + b] = s[t] - v;
    if (t == 255) btot[b] = s[255];
}

// ---- S2: exclusive scan of bucket totals -> bucket bases ----
__global__ __launch_bounds__(1024) void scanS2_kernel(
    const int* __restrict__ btot, int* __restrict__ bbase, int* __restrict__ row_ptr)
{
    __shared__ int s[1024];
    const int t = threadIdx.x;
    int v = (t < CB) ? btot[t] : 0;
    s[t] = v;
    __syncthreads();
    for (int off = 1; off < 1024; off <<= 1) {
        int u = (t >= off) ? s[t - off] : 0;
        __syncthreads();
        s[t] += u;
        __syncthreads();
    }
    if (t < CB) bbase[t] = s[t] - v;
    if (t == 0) row_ptr[N_NODES] = N_EDGES;
}

// ---- A3: coarse scatter (zero global atomics) ----
// rec_tmp (32B): w0..3 = ea f16x8, w4 = src, w5 = dst
__global__ __launch_bounds__(256) void scatterA_kernel(
    const int*   __restrict__ src,
    const int*   __restrict__ dst,
    const float* __restrict__ edge_attr,
    const int*   __restrict__ exclM,
    const int*   __restrict__ bbase,
    uint*        __restrict__ rec_tmp)
{
    __shared__ int cur[CB];
    const int t = threadIdx.x;
    for (int i = t; i < CB; i += 256)
        cur[i] = bbase[i] + exclM[blockIdx.x * CB + i];
    __syncthreads();
    const int e0 = blockIdx.x * A_EPB;
    const float4* ea4 = (const float4*)edge_attr;
    for (int j = 0; j < A_EPB; j += 256) {
        int e = e0 + j + t;
        if (e >= N_EDGES) continue;
        int dn = dst[e];
        int pos = atomicAdd(&cur[dn >> 7], 1);
        float4 a = ea4[(long)e * 2];
        float4 c = ea4[(long)e * 2 + 1];
        uint* r = rec_tmp + (size_t)pos * 8;
        *(uint4*)r = make_uint4(ph2(a.x, a.y), ph2(a.z, a.w),
                                ph2(c.x, c.y), ph2(c.z, c.w));
        *(uint2*)(r + 4) = make_uint2((uint)src[e], (uint)dn);
    }
}

// ---- B: per-bucket fine scatter -> SoA {ea16, srcf} + exact row_ptr ----
__global__ __launch_bounds__(256) void fineB_kernel(
    const uint* __restrict__ rec_tmp,
    const int*  __restrict__ bbase,
    int*        __restrict__ row_ptr,
    uint4*      __restrict__ ea16,
    int*        __restrict__ srcf)
{
    __shared__ int h[BKN];
    __shared__ int ex[BKN];
    const int t = threadIdx.x;
    const int b = blockIdx.x;
    const int e0 = bbase[b];
    const int e1 = (b == CB - 1) ? N_EDGES : bbase[b + 1];

    if (t < BKN) h[t] = 0;
    __syncthreads();
    for (int r = e0 + t; r < e1; r += 256)
        atomicAdd(&h[rec_tmp[(size_t)r * 8 + 5] & (BKN - 1)], 1);
    __syncthreads();
    if (t < BKN) ex[t] = h[t];
    __syncthreads();
    for (int off = 1; off < BKN; off <<= 1) {
        int u = (t < BKN && t >= off) ? ex[t - off] : 0;
        __syncthreads();
        if (t < BKN) ex[t] += u;
        __syncthreads();
    }
    if (t < BKN) {
        int excl = ex[t] - h[t];
        int n = b * BKN + t;
        if (n < N_NODES) row_ptr[n] = e0 + excl;
        h[t] = e0 + excl;
    }
    __syncthreads();
    for (int r = e0 + t; r < e1; r += 256) {
        const uint* rt = rec_tmp + (size_t)r * 8;
        uint4 ea = *(const uint4*)rt;
        uint2 sd = *(const uint2*)(rt + 4);
        int pos = atomicAdd(&h[sd.y & (BKN - 1)], 1);
        ea16[pos] = ea;
        srcf[pos] = (int)sd.x;
    }
}

// ---------------- fused GINE layer: f16 dot2 MLP, SoA records ----------------
__global__ __launch_bounds__(256) void gine_fused4_kernel(
    const ushort* __restrict__ xb_in, ushort* __restrict__ xb_out,
    float* __restrict__ f32_out, const int* __restrict__ row_ptr,
    const uint4* __restrict__ ea16, const int* __restrict__ srcf,
    const float* __restrict__ W, const float* __restrict__ b,
    const float* __restrict__ We, const float* __restrict__ be)
{
    __shared__ float W_s[D * D];
    const int t = threadIdx.x;
    for (int i = t; i < D * D; i += 256) W_s[i] = W[i];

    const int n = blockIdx.x * 8 + (t >> 5);
    const int d = t & 31;

    half2v wep[4];
#pragma unroll
    for (int k = 0; k < 4; ++k) {
        wep[k].x = (__fp16)We[(2 * k) * D + d];
        wep[k].y = (__fp16)We[(2 * k + 1) * D + d];
    }
    const float bed = be[d];
    const float bd  = b[d];
    __syncthreads();
    if (n >= N_NODES) return;

    const int row = row_ptr[n], rend = row_ptr[n + 1];
    float selfx = bf_us(xb_in[n * D + d]);

    float acc = 0.0f;
    for (int pos = row; pos < rend; pos += 8) {
        const int rem = rend - pos;
        // 8 edges: 128B coalesced ea + 32B src (8 lanes)
        uint eav = ((const uint*)ea16)[(size_t)pos * 4 + d];
        int srcv = (d < 8) ? srcf[pos + d] : 0;

        int srcs[8];
#pragma unroll
        for (int j = 0; j < 8; ++j) srcs[j] = __shfl(srcv, j, 32);
        const int s0 = srcs[0];

        float xv[8];
#pragma unroll
        for (int j = 0; j < 8; ++j) {
            int sj = (j < rem) ? srcs[j] : s0;
            xv[j] = bf_us(xb_in[sj * D + d]);
        }
#pragma unroll
        for (int j = 0; j < 8; ++j) {
            uint u0 = (uint)__shfl((int)eav, 4 * j, 32);
            uint u1 = (uint)__shfl((int)eav, 4 * j + 1, 32);
            uint u2 = (uint)__shfl((int)eav, 4 * j + 2, 32);
            uint u3 = (uint)__shfl((int)eav, 4 * j + 3, 32);
            float e = fdot2f(u3, wep[3],
                      fdot2f(u2, wep[2],
                      fdot2f(u1, wep[1],
                      fdot2f(u0, wep[0], bed))));
            float msg = fmaxf(xv[j] + e, 0.0f);
            acc += (j < rem) ? msg : 0.0f;
        }
    }

    float h = selfx + acc;
    float o = bd;
#pragma unroll
    for (int k = 0; k < D; ++k)
        o += __shfl(h, k, 32) * W_s[k * D + d];
    o = o > 0.0f ? o : NEG_SLOPE * o;
    xb_out[n * D + d] = (ushort)bf16_rne(o);
    if (f32_out) f32_out[n * D + d] = o;
}

// =================== mid-tier (r5 CSR build + bf16 layer) ===================
__global__ __launch_bounds__(256) void hist_kernel(
    const int* __restrict__ dst, int* __restrict__ deg)
{
    int i = blockIdx.x * 256 + threadIdx.x;
    if (i >= N_EDGES / 4) return;
    int4 dd = ((const int4*)dst)[i];
    atomicAdd(&deg[dd.x], 1);
    atomicAdd(&deg[dd.y], 1);
    atomicAdd(&deg[dd.z], 1);
    atomicAdd(&deg[dd.w], 1);
}

__global__ __launch_bounds__(1024) void scan_phase1(
    const int* __restrict__ deg, int* __restrict__ bsums)
{
    __shared__ int s[1024];
    int t = threadIdx.x;
    int i = blockIdx.x * 1024 + t;
    s[t] = (i < N_NODES) ? deg[i] : 0;
    __syncthreads();
    for (int off = 512; off > 0; off >>= 1) {
        if (t < off) s[t] += s[t + off];
        __syncthreads();
    }
    if (t == 0) bsums[blockIdx.x] = s[0];
}

__global__ __launch_bounds__(128) void scan_phase2(int* __restrict__ bsums)
{
    __shared__ int s[128];
    int t = threadIdx.x;
    int v = (t < NBLK) ? bsums[t] : 0;
    s[t] = v;
    __syncthreads();
    for (int off = 1; off < 128; off <<= 1) {
        int u = (t >= off) ? s[t - off] : 0;
        __syncthreads();
        s[t] += u;
        __syncthreads();
    }
    if (t < NBLK) bsums[t] = s[t] - v;
}

__global__ __launch_bounds__(1024) void scan_phase3(
    const int* __restrict__ deg, const int* __restrict__ bsums,
    int* __restrict__ row_ptr, int* __restrict__ offs)
{
    __shared__ int s[1024];
    int t = threadIdx.x;
    int i = blockIdx.x * 1024 + t;
    int v = (i < N_NODES) ? deg[i] : 0;
    s[t] = v;
    __syncthreads();
    for (int off = 1; off < 1024; off <<= 1) {
        int u = (t >= off) ? s[t - off] : 0;
        __syncthreads();
        s[t] += u;
        __syncthreads();
    }
    int excl = bsums[blockIdx.x] + s[t] - v;
    if (i < N_NODES) { row_ptr[i] = excl; offs[i] = excl; }
    else if (i == N_NODES) row_ptr[i] = excl;
}

__global__ __launch_bounds__(256) void scatter_rec_kernel(
    const int* __restrict__ src, const int* __restrict__ dst,
    const float* __restrict__ edge_attr, int* __restrict__ offs,
    uint* __restrict__ rec)
{
    int e = blockIdx.x * 256 + threadIdx.x;
    if (e >= N_EDGES) return;
    int pos = atomicAdd(&offs[dst[e]], 1);
    const float4* ea4 = (const float4*)edge_attr;
    float4 a = ea4[(long)e * 2];
    float4 c = ea4[(long)e * 2 + 1];
    uint* r = rec + (long)pos * 8;
    *(uint4*)r = make_uint4((uint)src[e], pack2(a.x, a.y), pack2(a.z, a.w), pack2(c.x, c.y));
    r[4] = pack2(c.z, c.w);
}

__global__ __launch_bounds__(256) void gine_fused2_kernel(
    const ushort* __restrict__ xb_in, ushort* __restrict__ xb_out,
    float* __restrict__ f32_out, const int* __restrict__ row_ptr,
    const uint* __restrict__ rec,
    const float* __restrict__ W, const float* __restrict__ b,
    const float* __restrict__ We, const float* __restrict__ be)
{
    __shared__ float W_s[D * D];
    __shared__ float We_s[ED * D];
    __shared__ float b_s[D];
    __shared__ float be_s[D];
    const int t = threadIdx.x;
    for (int i = t; i < D * D; i += 256) W_s[i] = W[i];
    if (t < ED * D) We_s[t] = We[t];
    if (t < D) { b_s[t] = b[t]; be_s[t] = be[t]; }
    __syncthreads();
    const int n = blockIdx.x * 8 + (t >> 5);
    const int d = t & 31;
    if (n >= N_NODES) return;
    float wer[ED];
#pragma unroll
    for (int k = 0; k < ED; ++k) wer[k] = We_s[k * D + d];
    const float bed = be_s[d];
    const int row = row_ptr[n], rend = row_ptr[n + 1];
    float selfx = bf_us(xb_in[n * D + d]);
    float acc = 0.0f;
    for (int pos = row; pos < rend; pos += 8) {
        const int rem = rend - pos;
        const uint2* rp = (const uint2*)(rec + (long)pos * 8);
        uint2 v = rp[d];
        int srcs[8];
#pragma unroll
        for (int j = 0; j < 8; ++j) srcs[j] = __shfl((int)v.x, 4 * j, 32);
        const int s0 = srcs[0];
        float xv[8];
#pragma unroll
        for (int j = 0; j < 8; ++j) {
            int sj = (j < rem) ? srcs[j] : s0;
            xv[j] = bf_us(xb_in[sj * D + d]);
        }
#pragma unroll
        for (int j = 0; j < 8; ++j) {
            uint u01 = (uint)__shfl((int)v.y, 4 * j, 32);
            uint u23 = (uint)__shfl((int)v.x, 4 * j + 1, 32);
            uint u45 = (uint)__shfl((int)v.y, 4 * j + 1, 32);
            uint u67 = (uint)__shfl((int)v.x, 4 * j + 2, 32);
            float e = bed;
            e += bf_lo(u01) * wer[0]; e += bf_hi(u01) * wer[1];
            e += bf_lo(u23) * wer[2]; e += bf_hi(u23) * wer[3];
            e += bf_lo(u45) * wer[4]; e += bf_hi(u45) * wer[5];
            e += bf_lo(u67) * wer[6]; e += bf_hi(u67) * wer[7];
            float msg = fmaxf(xv[j] + e, 0.0f);
            acc += (j < rem) ? msg : 0.0f;
        }
    }
    float h = selfx + acc;
    float o = b_s[d];
#pragma unroll
    for (int k = 0; k < D; ++k)
        o += __shfl(h, k, 32) * W_s[k * D + d];
    o = o > 0.0f ? o : NEG_SLOPE * o;
    xb_out[n * D + d] = (ushort)bf16_rne(o);
    if (f32_out) f32_out[n * D + d] = o;
}

// =================== round-1 fallback ===================
__global__ __launch_bounds__(256) void gine_edge_kernel(
    const float* __restrict__ x, const float* __restrict__ edge_attr,
    const float* __restrict__ We, const float* __restrict__ be,
    const int* __restrict__ src, const int* __restrict__ dst,
    float* __restrict__ agg)
{
    __shared__ float We_s[ED * D];
    __shared__ float be_s[D];
    int t = threadIdx.x;
    if (t < ED * D) We_s[t] = We[t];
    if (t < D) be_s[t] = be[t];
    __syncthreads();
    long gtid = (long)blockIdx.x * blockDim.x + t;
    int e = (int)(gtid >> 5), d = (int)(gtid & 31);
    if (e >= N_EDGES) return;
    int s = src[e], dn = dst[e];
    float acc = be_s[d];
#pragma unroll
    for (int k = 0; k < ED; ++k)
        acc += edge_attr[(long)e * ED + k] * We_s[k * D + d];
    float m = fmaxf(x[(long)s * D + d] + acc, 0.0f);
    atomicAdd(&agg[(long)dn * D + d], m);
}

__global__ __launch_bounds__(256) void gine_node_kernel(
    float* __restrict__ x, const float* __restrict__ agg,
    const float* __restrict__ W, const float* __restrict__ b)
{
    __shared__ float W_s[D * D];
    __shared__ float b_s[D];
    int t = threadIdx.x;
    for (int i = t; i < D * D; i += 256) W_s[i] = W[i];
    if (t < D) b_s[t] = b[t];
    __syncthreads();
    long gtid = (long)blockIdx.x * blockDim.x + t;
    int n = (int)(gtid >> 5), d = (int)(gtid & 31);
    if (n >= N_NODES) return;
    float h = x[(long)n * D + d] + agg[(long)n * D + d];
    float acc = b_s[d];
#pragma unroll
    for (int k = 0; k < D; ++k)
        acc += __shfl(h, k, D) * W_s[k * D + d];
    x[(long)n * D + d] = acc > 0.0f ? acc : NEG_SLOPE * acc;
}

// =================== launch ===================
extern "C" void kernel_launch(void* const* d_in, const int* in_sizes, int n_in,
                              void* d_out, int out_size, void* d_ws, size_t ws_size,
                              hipStream_t stream) {
    const float* x_in      = (const float*)d_in[0];
    const float* edge_attr = (const float*)d_in[1];
    const float* W         = (const float*)d_in[2];
    const float* b         = (const float*)d_in[3];
    const float* We        = (const float*)d_in[4];
    const float* be        = (const float*)d_in[5];
    const int*   ei        = (const int*)d_in[6];
    const int* src = ei;
    const int* dst = ei + N_EDGES;

    const size_t xbytes  = (size_t)N_NODES * D * sizeof(float);
    const size_t xbbytes = (size_t)N_NODES * D * sizeof(ushort);  // 6.4 MB

    auto align = [](size_t v) { return (v + 255) & ~(size_t)255; };
    size_t off_xba  = 0;
    size_t off_rp   = align(off_xba + xbbytes);                    // row_ptr N+1
    size_t off_cnt  = align(off_rp + (N_NODES + 1) * sizeof(int)); // cntM / deg
    size_t off_excl = align(off_cnt + (size_t)A_NB * CB * sizeof(int));  // exclM / offs
    size_t off_bt   = align(off_excl + (size_t)A_NB * CB * sizeof(int)); // btot / bsums
    size_t off_bb   = align(off_bt + CB * sizeof(int));            // bbase
    size_t off_ea   = align(off_bb + CB * sizeof(int));            // ea16 (E+8)*16B
    size_t off_src  = align(off_ea + ((size_t)N_EDGES + 8) * 16);  // srcf (E+8)*4B
    size_t off_rtmp = align(off_src + ((size_t)N_EDGES + 8) * 4);  // rec_tmp E*32B / xbB
    size_t need_big = off_rtmp + (size_t)N_EDGES * 32 + 256;
    // mid tier: rec (E*32B) at off_ea, xbB after
    size_t off_mrec = off_ea;
    size_t off_mxbb = align(off_mrec + ((size_t)N_EDGES + 8) * 32);
    size_t need_mid = off_mxbb + xbbytes + 256;

    char* ws = (char*)d_ws;
    ushort* xbA    = (ushort*)(ws + off_xba);
    int*   row_ptr = (int*)   (ws + off_rp);
    int*   cntM    = (int*)   (ws + off_cnt);
    int*   exclM   = (int*)   (ws + off_excl);
    int*   btot    = (int*)   (ws + off_bt);
    int*   bbase   = (int*)   (ws + off_bb);
    uint4* ea16    = (uint4*) (ws + off_ea);
    int*   srcf    = (int*)   (ws + off_src);
    uint*  rec_tmp = (uint*)  (ws + off_rtmp);
    ushort* xbB    = (ushort*)(ws + off_rtmp);   // aliases rec_tmp (dead after fineB)
    float* xout    = (float*)d_out;

    if (ws_size >= need_big) {
        pack_x_kernel<<<(N_NODES * D / 4 + 255) / 256, 256, 0, stream>>>(x_in, xbA);
        countA_kernel<<<A_NB, 256, 0, stream>>>(dst, cntM);
        scanS1_kernel<<<CB, 256, 0, stream>>>(cntM, exclM, btot);
        scanS2_kernel<<<1, 1024, 0, stream>>>(btot, bbase, row_ptr);
        scatterA_kernel<<<A_NB, 256, 0, stream>>>(src, dst, edge_attr, exclM, bbase, rec_tmp);
        fineB_kernel<<<CB, 256, 0, stream>>>(rec_tmp, bbase, row_ptr, ea16, srcf);

        dim3 blk(256), grid((N_NODES + 7) / 8);
        gine_fused4_kernel<<<grid, blk, 0, stream>>>(xbA, xbB, nullptr, row_ptr, ea16, srcf,
            W, b, We, be);
        gine_fused4_kernel<<<grid, blk, 0, stream>>>(xbB, xbA, nullptr, row_ptr, ea16, srcf,
            W + D * D, b + D, We + ED * D, be + D);
        gine_fused4_kernel<<<grid, blk, 0, stream>>>(xbA, xbB, xout, row_ptr, ea16, srcf,
            W + 2 * D * D, b + 2 * D, We + 2 * ED * D, be + 2 * D);
    } else if (ws_size >= need_mid) {
        int* deg  = cntM;
        int* offs = exclM;
        int* bsums = btot;
        uint* rec = (uint*)(ws + off_mrec);
        ushort* xbBm = (ushort*)(ws + off_mxbb);
        pack_x_kernel<<<(N_NODES * D / 4 + 255) / 256, 256, 0, stream>>>(x_in, xbA);
        hipMemsetAsync(deg, 0, N_NODES * sizeof(int), stream);
        hist_kernel<<<(N_EDGES / 4 + 255) / 256, 256, 0, stream>>>(dst, deg);
        scan_phase1<<<NBLK, 1024, 0, stream>>>(deg, bsums);
        scan_phase2<<<1, 128, 0, stream>>>(bsums);
        scan_phase3<<<NBLK, 1024, 0, stream>>>(deg, bsums, row_ptr, offs);
        scatter_rec_kernel<<<(N_EDGES + 255) / 256, 256, 0, stream>>>(
            src, dst, edge_attr, offs, rec);
        dim3 blk(256), grid((N_NODES + 7) / 8);
        gine_fused2_kernel<<<grid, blk, 0, stream>>>(xbA, xbBm, nullptr, row_ptr, rec,
            W, b, We, be);
        gine_fused2_kernel<<<grid, blk, 0, stream>>>(xbBm, xbA, nullptr, row_ptr, rec,
            W + D * D, b + D, We + ED * D, be + D);
        gine_fused2_kernel<<<grid, blk, 0, stream>>>(xbA, xbBm, xout, row_ptr, rec,
            W + 2 * D * D, b + 2 * D, We + 2 * ED * D, be + 2 * D);
    } else {
        float* x = (float*)d_out;
        float* agg = (float*)d_ws;
        hipMemcpyAsync(x, x_in, xbytes, hipMemcpyDeviceToDevice, stream);
        dim3 eblk(256), egrid(((long)N_EDGES * D + 255) / 256);
        dim3 nblk(256), ngrid(((long)N_NODES * D + 255) / 256);
        for (int l = 0; l < 3; ++l) {
            hipMemsetAsync(agg, 0, xbytes, stream);
            gine_edge_kernel<<<egrid, eblk, 0, stream>>>(
                x, edge_attr, We + (size_t)l * ED * D, be + (size_t)l * D, src, dst, agg);
            gine_node_kernel<<<ngrid, nblk, 0, stream>>>(
                x, agg, W + (size_t)l * D * D, b + (size_t)l * D);
        }
    }
}